// Round 2
// baseline (361.912 us; speedup 1.0000x reference)
//
#include <hip/hip_runtime.h>
#include <hip/hip_bf16.h>

#define HWN    1024
#define CCH    512
#define NBATCH 16
#define NGROUP 32
#define EPSV   1e-5f

using bf16 = __hip_bfloat16;
typedef __attribute__((ext_vector_type(4))) float f32x4;
typedef __attribute__((ext_vector_type(8))) short s16x8;

// Runtime-dtyped element access: c==1 -> fp32, c==0 -> bf16 storage.
__device__ __forceinline__ float ldv(const void* p, long i, int c) {
    return c ? ((const float*)p)[i] : __bfloat162float(((const bf16*)p)[i]);
}
__device__ __forceinline__ void stv(void* p, long i, int c, float v) {
    if (c) ((float*)p)[i] = v;
    else   ((bf16*)p)[i]  = __float2bfloat16(v);
}

// async global->LDS, 16B per lane; lds dest = wave-uniform base + lane*16
__device__ __forceinline__ void glds16(const void* g, void* l) {
    __builtin_amdgcn_global_load_lds(
        (const __attribute__((address_space(1))) void*)g,
        (__attribute__((address_space(3))) void*)l, 16, 0, 0);
}

// ---------------------------------------------------------------------------
// Storage dtype detector (proven in R3). flag=1 => fp32 storage.
// ---------------------------------------------------------------------------
__global__ __launch_bounds__(256) void detect_kernel(const void* __restrict__ x,
                                                     int* __restrict__ flag)
{
    const int tid = threadIdx.x;
    const unsigned short* h = (const unsigned short*)x;
    int ok = 0;
    for (int i = tid; i < 4096; i += 256) {
        int e = (h[2 * i] >> 7) & 0xFF;
        if (e >= 100 && e <= 135) ok++;
    }
    __shared__ int red[256];
    red[tid] = ok; __syncthreads();
    for (int off = 128; off > 0; off >>= 1) {
        if (tid < off) red[tid] += red[tid + off];
        __syncthreads();
    }
    if (tid == 0) flag[0] = (red[0] < 2458) ? 1 : 0;
}

// ---------------------------------------------------------------------------
// GroupNorm stats: one block per (batch, group) -> (mean, rstd). f4-vectorized.
// ---------------------------------------------------------------------------
__global__ __launch_bounds__(256) void gn_stats_kernel(const void* __restrict__ x,
                                                       const int* __restrict__ flag,
                                                       float2* __restrict__ stats)
{
    const int f = flag[0];
    const int b = blockIdx.x >> 5, g = blockIdx.x & 31;
    const long base = ((long)b * CCH + (long)g * (CCH / NGROUP)) * HWN;
    const int tid = threadIdx.x;
    const int n = (CCH / NGROUP) * HWN;       // 16384
    float s = 0.f, ss = 0.f;
    if (f) {
        const float4* xp = (const float4*)((const float*)x + base);
        #pragma unroll
        for (int k = 0; k < 16; ++k) {
            float4 u = xp[tid + k * 256];
            s  += u.x + u.y + u.z + u.w;
            ss += u.x * u.x + u.y * u.y + u.z * u.z + u.w * u.w;
        }
    } else {
        for (int i = tid; i < n; i += 256) {
            float v = ldv(x, base + i, 0);
            s += v; ss += v * v;
        }
    }
    __shared__ float r1[256], r2[256];
    r1[tid] = s; r2[tid] = ss; __syncthreads();
    for (int off = 128; off > 0; off >>= 1) {
        if (tid < off) { r1[tid] += r1[tid + off]; r2[tid] += r2[tid + off]; }
        __syncthreads();
    }
    if (tid == 0) {
        float mean = r1[0] / n;
        float var  = r2[0] / n - mean * mean;
        stats[blockIdx.x] = make_float2(mean, rsqrtf(var + EPSV));
    }
}

// ---------------------------------------------------------------------------
// Weight/bias prep: Wqk = [Wq;Wk] bf16 [1024][512]; Wv,Wo bf16; biases f32.
// ---------------------------------------------------------------------------
__global__ __launch_bounds__(256)
void prep_kernel(const void* __restrict__ Wq, const void* __restrict__ Wk,
                 const void* __restrict__ Wv, const void* __restrict__ Wo,
                 const void* __restrict__ bq, const void* __restrict__ bk,
                 const void* __restrict__ bv, const void* __restrict__ bo,
                 const int* __restrict__ flag,
                 bf16* __restrict__ Wqk, bf16* __restrict__ Wvb, bf16* __restrict__ Wob,
                 float* __restrict__ bQK, float* __restrict__ bV, float* __restrict__ bO)
{
    const int f = flag[0];
    const int idx = blockIdx.x * 256 + threadIdx.x;
    if (idx < 524288) {
        const int r = idx >> 9, c = idx & 511;
        float v = (r < 512) ? ldv(Wq, (long)r * 512 + c, f)
                            : ldv(Wk, (long)(r - 512) * 512 + c, f);
        Wqk[idx] = __float2bfloat16(v);
    } else if (idx < 786432) {
        Wvb[idx - 524288] = __float2bfloat16(ldv(Wv, idx - 524288, f));
    } else if (idx < 1048576) {
        Wob[idx - 786432] = __float2bfloat16(ldv(Wo, idx - 786432, f));
    } else {
        const int j = idx - 1048576;
        if      (j < 512)  bQK[j]        = ldv(bq, j, f);
        else if (j < 1024) bQK[j]        = ldv(bk, j - 512, f);
        else if (j < 1536) bV[j - 1024]  = ldv(bv, j - 1024, f);
        else if (j < 2048) bO[j - 1536]  = ldv(bo, j - 1536, f);
    }
}

// ---------------------------------------------------------------------------
// GN+SiLU with transpose: x [c][i] (flag dtype) -> xn' [i][c] bf16.
// ---------------------------------------------------------------------------
__global__ __launch_bounds__(256)
void gn_apply_kernel(const void* __restrict__ x, const int* __restrict__ flag,
                     const float2* __restrict__ stats,
                     const void* __restrict__ gamma, const void* __restrict__ beta,
                     bf16* __restrict__ xn, int zb)
{
    const int f = flag[0];
    __shared__ float t[64][65];
    const int bz = blockIdx.z;
    const int bx = zb + bz;
    const int i0 = blockIdx.x * 64;
    const int c0 = blockIdx.y * 64;
    const int tid = threadIdx.x;
    const int il = tid & 63;
    const int hq = tid >> 6;              // 0..3
    #pragma unroll
    for (int r = 0; r < 16; ++r) {
        const int cl = r * 4 + hq;
        const int c = c0 + cl;
        const float2 st = stats[bx * NGROUP + (c >> 4)];
        const float ga = ldv(gamma, c, f), be = ldv(beta, c, f);
        float v = ldv(x, (long)bx * CCH * HWN + (long)c * HWN + i0 + il, f);
        v = (v - st.x) * st.y * ga + be;
        t[cl][il] = v / (1.f + __expf(-v));     // SiLU
    }
    __syncthreads();
    #pragma unroll
    for (int r = 0; r < 16; ++r) {
        const int ii = r * 4 + hq;
        xn[(long)bz * CCH * HWN + (long)(i0 + ii) * CCH + c0 + il] =
            __float2bfloat16(t[il][ii]);
    }
}

// ---------------------------------------------------------------------------
// Legacy 128x128 MFMA GEMM — kept for tier2/3 fallback paths (proven).
// ---------------------------------------------------------------------------
template<bool FINAL, bool EXPS, bool RDIV>
__global__ __launch_bounds__(256)
void mfma_gemm(const bf16* __restrict__ A, const bf16* __restrict__ B,
               void* __restrict__ C, int K,
               int lda, int ldb, int ldc,
               long sA, long sB, long sC, int z0,
               const float* __restrict__ rowBias, const float* __restrict__ colBias,
               float alpha, const void* __restrict__ resid, long sR,
               const int* __restrict__ flag)
{
    __shared__ bf16 lA[2][128 * 32];
    __shared__ bf16 lB[2][128 * 32];

    const int gx = gridDim.x, gy = gridDim.y;
    const int nwg = gx * gy * (int)gridDim.z;
    const int lin = blockIdx.x + gx * (blockIdx.y + gy * blockIdx.z);
    const int qq = nwg >> 3, rr = nwg & 7;
    const int xc = lin & 7, sq = lin >> 3;
    const int nl = (xc < rr ? xc * (qq + 1) : rr * (qq + 1) + (xc - rr) * qq) + sq;
    const int bxi = nl % gx;
    const int tt  = nl / gx;
    const int byi = tt % gy;
    const int bzi = tt / gy;

    const int tid = threadIdx.x;
    const int w   = tid >> 6;
    const int l   = tid & 63;
    const int ln  = l & 15;
    const int qd  = l >> 4;
    const int wm  = (w >> 1) * 64;
    const int wn  = (w & 1) * 64;
    const int zA  = z0 + bzi;

    const bf16* Ab = A + (long)zA * sA;
    const bf16* Bb = B + (long)zA * sB;
    const int m0 = byi * 128;
    const int n0 = bxi * 128;

    const int sr   = l >> 2;
    const int kswz = ((l & 3) ^ ((l >> 3) & 3)) * 8;
    const bf16* gA0 = Ab + (long)(m0 + w * 16 + sr) * lda + kswz;
    const bf16* gA1 = gA0 + (long)64 * lda;
    const bf16* gB0 = Bb + (long)(n0 + w * 16 + sr) * ldb + kswz;
    const bf16* gB1 = gB0 + (long)64 * ldb;

    f32x4 acc[4][4];
    #pragma unroll
    for (int i = 0; i < 4; ++i)
        #pragma unroll
        for (int j = 0; j < 4; ++j)
            acc[i][j] = (f32x4){0.f, 0.f, 0.f, 0.f};

    float rsum[4] = {0.f, 0.f, 0.f, 0.f};
    const int swA = (qd ^ ((ln >> 1) & 3)) * 8;

    glds16(gA0, &lA[0][w * 512]);
    glds16(gA1, &lA[0][2048 + w * 512]);
    glds16(gB0, &lB[0][w * 512]);
    glds16(gB1, &lB[0][2048 + w * 512]);

    const int NK = K >> 5;
    for (int t = 0; t < NK; ++t) {
        const int p = t & 1;
        __syncthreads();
        if (t + 1 < NK) {
            const int kk = (t + 1) << 5;
            glds16(gA0 + kk, &lA[p ^ 1][w * 512]);
            glds16(gA1 + kk, &lA[p ^ 1][2048 + w * 512]);
            glds16(gB0 + kk, &lB[p ^ 1][w * 512]);
            glds16(gB1 + kk, &lB[p ^ 1][2048 + w * 512]);
        }
        s16x8 af[4], bfr[4];
        #pragma unroll
        for (int i = 0; i < 4; ++i)
            af[i] = *(const s16x8*)&lA[p][(wm + i * 16 + ln) * 32 + swA];
        #pragma unroll
        for (int j = 0; j < 4; ++j)
            bfr[j] = *(const s16x8*)&lB[p][(wn + j * 16 + ln) * 32 + swA];
        if (RDIV) {
            #pragma unroll
            for (int i = 0; i < 4; ++i) {
                union { s16x8 v; unsigned u[4]; } cv; cv.v = af[i];
                #pragma unroll
                for (int wd = 0; wd < 4; ++wd) {
                    rsum[i] += __uint_as_float(cv.u[wd] << 16);
                    rsum[i] += __uint_as_float(cv.u[wd] & 0xffff0000u);
                }
            }
        }
        #pragma unroll
        for (int i = 0; i < 4; ++i)
            #pragma unroll
            for (int j = 0; j < 4; ++j)
                acc[i][j] = __builtin_amdgcn_mfma_f32_16x16x32_bf16(
                    af[i], bfr[j], acc[i][j], 0, 0, 0);
    }

    if (RDIV) {
        #pragma unroll
        for (int i = 0; i < 4; ++i) {
            rsum[i] += __shfl_xor(rsum[i], 16);
            rsum[i] += __shfl_xor(rsum[i], 32);
        }
    }

    const int f = (FINAL && flag) ? flag[0] : 0;
    #pragma unroll
    for (int i = 0; i < 4; ++i) {
        #pragma unroll
        for (int r = 0; r < 4; ++r) {
            const int m = m0 + wm + i * 16 + qd * 4 + r;
            const float rb = rowBias ? rowBias[m] : 0.f;
            const float inv = RDIV ? (1.f / __shfl(rsum[i], qd * 4 + r)) : 1.f;
            #pragma unroll
            for (int j = 0; j < 4; ++j) {
                const int n = n0 + wn + j * 16 + ln;
                float v = alpha * acc[i][j][r] + rb;
                if (colBias) v += colBias[n];
                if (EXPS) v = __expf(fminf(v, 60.f));
                if (RDIV) v *= inv;
                const long idx = (long)zA * sC + (long)m * ldc + n;
                if (FINAL) {
                    if (resid) v += ldv(resid, (long)zA * sR + (long)m * ldc + n, f);
                    stv(C, idx, f, v);
                } else {
                    ((bf16*)C)[idx] = __float2bfloat16(v);
                }
            }
        }
    }
}

// ---------------------------------------------------------------------------
// R7: 256x256(BM) x BN(=NBF*64) tile, BK=64, 8 waves (2M x 4N), 512 threads.
// Double-buffered full K-tiles in LDS (128 KB @ NBF=4), glds16 staging with
// counted vmcnt (never 0 in-loop, T4) + raw s_barrier. XOR swizzle keeps
// ds_read_b128 at 2-way bank aliasing; inverse swizzle is pre-applied to the
// GLOBAL source address (rule #21: linear LDS dest + permuted source).
//   C[m][n] = alpha * sum_k A[m][k]*B[n][k]  (+biases/epilogues as flagged)
// EXPS: store exp(clamp(v,60)) — softmax numerator (denominator deferred).
// RDIV: divide by row-sum of A computed in-register from the A-fragments
//       (lane (ln,qd) covers chunk qd of every 32-k block; xor16+xor32).
// SPLITN: C/resid column index n maps to batch-split layout (n>>10 = batch).
// ---------------------------------------------------------------------------
template<int NBF, bool FINAL, bool EXPS, bool RDIV, bool SPLITN>
__global__ __launch_bounds__(512, 2)
void gemm256(const bf16* __restrict__ A, const bf16* __restrict__ B,
             void* __restrict__ C, int K,
             int lda, int ldb, int ldc,
             long sA, long sB, long sC,
             const float* __restrict__ rowBias, const float* __restrict__ colBias,
             float alpha, const void* __restrict__ resid, long sR,
             const int* __restrict__ flag)
{
    constexpr int BN = NBF * 64;
    __shared__ bf16 lA[2][256 * 64];
    __shared__ bf16 lB[2][BN * 64];

    // XCD-bijective chunk swizzle (nwg=256 here: 32 contiguous tiles per XCD)
    const int gx = gridDim.x, gy = gridDim.y;
    const int nwg = gx * gy * (int)gridDim.z;
    const int lin = blockIdx.x + gx * (blockIdx.y + gy * blockIdx.z);
    const int qq = nwg >> 3, rr = nwg & 7;
    const int xc = lin & 7, sq = lin >> 3;
    const int nl = (xc < rr ? xc * (qq + 1) : rr * (qq + 1) + (xc - rr) * qq) + sq;
    const int bxi = nl % gx;
    const int tt  = nl / gx;
    const int byi = tt % gy;
    const int zA  = tt / gy;

    const int tid = threadIdx.x;
    const int w   = tid >> 6;                 // 0..7
    const int l   = tid & 63;
    const int ln  = l & 15;
    const int qd  = l >> 4;                   // 0..3
    const int wm  = (w >> 2) * 128;           // 0 / 128
    const int wn  = (w & 3) * (NBF * 16);     // 4 N-groups

    const bf16* Ab = A + (long)zA * sA;
    const bf16* Bb = B + (long)zA * sB;
    const int m0 = byi * 256;
    const int n0 = bxi * BN;

    // staging source: lane l covers row (l>>3) (+8 per wave-instr slot),
    // 16B chunk (l&7)^(l>>3) of the 64-elem row (inverse of the read swizzle)
    const int srow = l >> 3;
    const int kch  = ((l & 7) ^ srow) * 8;
    const bf16* gA = Ab + (long)(m0 + srow) * lda + kch;
    const bf16* gB = Bb + (long)(n0 + srow) * ldb + kch;

    auto stage = [&](int bb, int t) {
        const long ko = (long)t * 64;
        #pragma unroll
        for (int j = 0; j < 4; ++j)
            glds16(gA + (long)((j * 8 + w) * 8) * lda + ko,
                   &lA[bb][(j * 8 + w) * 512]);
        #pragma unroll
        for (int j = 0; j < NBF; ++j)
            glds16(gB + (long)((j * 8 + w) * 8) * ldb + ko,
                   &lB[bb][(j * 8 + w) * 512]);
    };

    f32x4 acc[8][NBF];
    #pragma unroll
    for (int i = 0; i < 8; ++i)
        #pragma unroll
        for (int j = 0; j < NBF; ++j)
            acc[i][j] = (f32x4){0.f, 0.f, 0.f, 0.f};
    float rsum[8];
    #pragma unroll
    for (int i = 0; i < 8; ++i) rsum[i] = 0.f;

    stage(0, 0);                               // prologue

    const int NT = K >> 6;
    for (int t = 0; t < NT; ++t) {
        const int cur = t & 1;
        if (t + 1 < NT) {
            stage(cur ^ 1, t + 1);             // prefetch next K-tile
            // tile t's loads landed; the 4+NBF just-issued stay in flight
            asm volatile("s_waitcnt vmcnt(%0)" :: "i"(4 + NBF) : "memory");
        } else {
            asm volatile("s_waitcnt vmcnt(0)" ::: "memory");
        }
        asm volatile("s_barrier" ::: "memory");   // tile t visible to all waves

        #pragma unroll
        for (int ks = 0; ks < 2; ++ks) {
            s16x8 af[8], bfr[NBF];
            const int swz = ((ks * 4 + qd) ^ (l & 7)) * 8;
            #pragma unroll
            for (int i = 0; i < 8; ++i)
                af[i] = *(const s16x8*)&lA[cur][(wm + i * 16 + ln) * 64 + swz];
            #pragma unroll
            for (int j = 0; j < NBF; ++j)
                bfr[j] = *(const s16x8*)&lB[cur][(wn + j * 16 + ln) * 64 + swz];
            if (RDIV) {                        // softmax denom partials (VALU)
                #pragma unroll
                for (int i = 0; i < 8; ++i) {
                    union { s16x8 v; unsigned u[4]; } cv; cv.v = af[i];
                    #pragma unroll
                    for (int wd = 0; wd < 4; ++wd) {
                        rsum[i] += __uint_as_float(cv.u[wd] << 16);
                        rsum[i] += __uint_as_float(cv.u[wd] & 0xffff0000u);
                    }
                }
            }
            #pragma unroll
            for (int i = 0; i < 8; ++i)
                #pragma unroll
                for (int j = 0; j < NBF; ++j)
                    acc[i][j] = __builtin_amdgcn_mfma_f32_16x16x32_bf16(
                        af[i], bfr[j], acc[i][j], 0, 0, 0);
        }
        asm volatile("s_waitcnt lgkmcnt(0)" ::: "memory"); // my LDS reads done
        asm volatile("s_barrier" ::: "memory");   // all waves done with buf cur
    }

    if (RDIV) {
        #pragma unroll
        for (int i = 0; i < 8; ++i) {
            rsum[i] += __shfl_xor(rsum[i], 16);
            rsum[i] += __shfl_xor(rsum[i], 32);
        }
    }

    // epilogue: C/D layout col = lane&15, row = qd*4 + reg  [m89]
    const int f = (FINAL && flag) ? flag[0] : 0;
    #pragma unroll
    for (int i = 0; i < 8; ++i) {
        #pragma unroll
        for (int r = 0; r < 4; ++r) {
            const int m = m0 + wm + i * 16 + qd * 4 + r;
            const float rb = rowBias ? rowBias[m] : 0.f;
            const float inv = RDIV ? (1.f / __shfl(rsum[i], qd * 4 + r)) : 1.f;
            #pragma unroll
            for (int j = 0; j < NBF; ++j) {
                const int n = n0 + wn + j * 16 + ln;
                float v = alpha * acc[i][j][r] + rb;
                if (colBias) v += colBias[n];
                if (EXPS) v = __expf(fminf(v, 60.f));
                if (RDIV) v *= inv;
                long idx, ridx;
                if (SPLITN) {
                    idx  = (long)(n >> 10) * sC + (long)m * ldc + (n & 1023);
                    ridx = (long)(n >> 10) * sR + (long)m * ldc + (n & 1023);
                } else {
                    idx  = (long)zA * sC + (long)m * ldc + n;
                    ridx = (long)zA * sR + (long)m * ldc + n;
                }
                if (FINAL) {
                    if (resid) v += ldv(resid, ridx, f);
                    stv(C, idx, f, v);
                } else {
                    ((bf16*)C)[idx] = __float2bfloat16(v);
                }
            }
        }
    }
}

// ---------------------------------------------------------------------------
extern "C" void kernel_launch(void* const* d_in, const int* in_sizes, int n_in,
                              void* d_out, int out_size, void* d_ws, size_t ws_size,
                              hipStream_t stream)
{
    const long NX = (long)NBATCH * CCH * HWN;
    int ix, iWq, ibq, iWk, ibk, iWv, ibv, iWo, ibo, iga, ibe;
    if (in_sizes[0] == NX) {
        ix = 0; iWq = 1; ibq = 2; iWk = 3; ibk = 4; iWv = 5; ibv = 6;
        iWo = 7; ibo = 8; iga = 9; ibe = 10;
    } else {
        iWk = 0; iWo = 1; iWq = 2; iWv = 3; ibe = 4; ibk = 5; ibo = 6;
        ibq = 7; ibv = 8; iga = 9; ix = 10;
    }
    const void* x     = d_in[ix];
    const void* Wq    = d_in[iWq];
    const void* bq    = d_in[ibq];
    const void* Wk    = d_in[iWk];
    const void* bk    = d_in[ibk];
    const void* Wv    = d_in[iWv];
    const void* bv    = d_in[ibv];
    const void* Wo    = d_in[iWo];
    const void* bo    = d_in[ibo];
    const void* gamma = d_in[iga];
    const void* beta  = d_in[ibe];

    const long CHW = (long)CCH * HWN;      // 524288
    const long NN  = (long)HWN * HWN;      // 1048576
    const size_t MB = 1ull << 20;
    char* ws = (char*)d_ws;

    bf16*   Wqk   = (bf16*)ws;                         // 1 MB
    bf16*   Wvb   = (bf16*)(ws + MB);                  // 0.5 MB
    bf16*   Wob   = (bf16*)(ws + MB + MB / 2);         // 0.5 MB
    float*  bQK   = (float*)(ws + 2 * MB);
    float*  bV    = (float*)(ws + 2 * MB + 4096);
    float*  bO    = (float*)(ws + 2 * MB + 6144);
    float2* stats = (float2*)(ws + 2 * MB + 8192);     // 4 KB
    int*    flag  = (int*)(ws + 2 * MB + 12288);

    dim3 blk(256);
    dim3 blk512(512);
    const float scale = 0.044194173824159216f;   // 512^-0.5
    const float* FNUL = nullptr;
    const void*  VNUL = nullptr;

    detect_kernel<<<dim3(1), blk, 0, stream>>>(x, flag);
    gn_stats_kernel<<<dim3(NBATCH * NGROUP), blk, 0, stream>>>(x, flag, stats);
    prep_kernel<<<dim3(4104), blk, 0, stream>>>(Wq, Wk, Wv, Wo, bq, bk, bv, bo,
                                                flag, Wqk, Wvb, Wob, bQK, bV, bO);

    const int tier = (ws_size >= 100 * MB) ? 1 : (ws_size >= 70 * MB) ? 2 : 3;

    if (tier == 1) {
        bf16* xn = (bf16*)(ws + 3 * MB);      // 16 MB [b*1024+i][c]
        bf16* Vt = (bf16*)(ws + 19 * MB);     // 16 MB [c][b*1024+j]
        bf16* QK = (bf16*)(ws + 35 * MB);     // 32 MB [b*1024+i][1024]
        bf16* S  = (bf16*)(ws + 67 * MB);     // 32 MB [b][i][j]
        bf16* O  = xn;                        // overlay: xn dead after V GEMM

        gn_apply_kernel<<<dim3(16, 8, NBATCH), blk, 0, stream>>>(
            x, flag, stats, gamma, beta, xn, 0);

        // QK' = xn' @ [Wq;Wk]^T + bias  (merged: M=16384, N=1024, K=512)
        gemm256<4, false, false, false, false><<<dim3(4, 64, 1), blk512, 0, stream>>>(
            xn, Wqk, QK, 512, 512, 512, 1024, 0L, 0L, 0L,
            FNUL, bQK, 1.f, VNUL, 0L, nullptr);
        // Vt[c][b*1024+j] = Wv @ gn(x)  (merged: M=512, N=16384, K=512)
        gemm256<2, false, false, false, false><<<dim3(128, 2, 1), blk512, 0, stream>>>(
            Wvb, xn, Vt, 512, 512, 512, 16384, 0L, 0L, 0L,
            bV, FNUL, 1.f, VNUL, 0L, nullptr);
        // S~ = exp(scale * Q' K'^T)  (per batch: M=N=1024, K=512)
        gemm256<4, false, true, false, false><<<dim3(4, 4, NBATCH), blk512, 0, stream>>>(
            QK, QK + 512, S, 512, 1024, 1024, 1024, NN, NN, NN,
            FNUL, FNUL, scale, VNUL, 0L, nullptr);
        // O' = (S~ @ Vt^T) / rowsum(S~)  (per batch: M=1024, N=512, K=1024)
        gemm256<2, false, false, true, false><<<dim3(4, 4, NBATCH), blk512, 0, stream>>>(
            S, Vt, O, 1024, 1024, 16384, 512, NN, 1024L, CHW,
            FNUL, FNUL, 1.f, VNUL, 0L, nullptr);
        // out = Wo @ O'^T + bo + x  (merged-N: M=512, N=16384, K=512)
        gemm256<2, true, false, false, true><<<dim3(128, 2, 1), blk512, 0, stream>>>(
            Wob, O, d_out, 512, 512, 512, 1024, 0L, 0L, CHW,
            bO, FNUL, 1.f, x, CHW, flag);
    } else if (tier == 2) {
        bf16* xn = (bf16*)(ws + 3 * MB);      // 16 MB [i][c] per batch
        bf16* V  = (bf16*)(ws + 19 * MB);     // 16 MB [c][j] per batch
        bf16* QK = (bf16*)(ws + 35 * MB);     // 32 MB [i][1024] per batch
        bf16* S  = (bf16*)(ws + 67 * MB);     // 2 MB
        bf16* O  = xn;

        gn_apply_kernel<<<dim3(16, 8, NBATCH), blk, 0, stream>>>(
            x, flag, stats, gamma, beta, xn, 0);
        mfma_gemm<false, false, false><<<dim3(8, 8, NBATCH), blk, 0, stream>>>(
            xn, Wqk, QK, 512, 512, 512, 1024, CHW, 0L, NN, 0,
            FNUL, bQK, 1.f, VNUL, 0L, nullptr);
        mfma_gemm<false, false, false><<<dim3(8, 4, NBATCH), blk, 0, stream>>>(
            Wvb, xn, V, 512, 512, 512, 1024, 0L, CHW, CHW, 0,
            bV, FNUL, 1.f, VNUL, 0L, nullptr);
        for (int b = 0; b < NBATCH; ++b) {
            mfma_gemm<false, true, false><<<dim3(8, 8, 1), blk, 0, stream>>>(
                QK, QK + 512, S, 512, 1024, 1024, 1024, NN, NN, 0L, b,
                FNUL, FNUL, scale, VNUL, 0L, nullptr);
            mfma_gemm<false, false, true><<<dim3(4, 8, 1), blk, 0, stream>>>(
                S, V, O, 1024, 1024, 1024, 512, 0L, CHW, CHW, b,
                FNUL, FNUL, 1.f, VNUL, 0L, nullptr);
        }
        mfma_gemm<true, false, false><<<dim3(8, 4, NBATCH), blk, 0, stream>>>(
            Wob, O, d_out, 512, 512, 512, 1024, 0L, CHW, CHW, 0,
            bO, FNUL, 1.f, x, CHW, flag);
    } else {
        // tier 3: fully per-batch (ws >= 9 MB)
        bf16* xn = (bf16*)(ws + 3 * MB);      // 1 MB
        bf16* V  = (bf16*)(ws + 4 * MB);      // 1 MB
        bf16* QK = (bf16*)(ws + 5 * MB);      // 2 MB
        bf16* S  = (bf16*)(ws + 7 * MB);      // 2 MB
        bf16* O  = xn;
        for (int b = 0; b < NBATCH; ++b) {
            gn_apply_kernel<<<dim3(16, 8, 1), blk, 0, stream>>>(
                x, flag, stats, gamma, beta, xn, b);
            mfma_gemm<false, false, false><<<dim3(8, 8, 1), blk, 0, stream>>>(
                xn, Wqk, QK, 512, 512, 512, 1024, 0L, 0L, 0L, 0,
                FNUL, bQK, 1.f, VNUL, 0L, nullptr);
            mfma_gemm<false, false, false><<<dim3(8, 4, 1), blk, 0, stream>>>(
                Wvb, xn, V, 512, 512, 512, 1024, 0L, 0L, 0L, 0,
                bV, FNUL, 1.f, VNUL, 0L, nullptr);
            mfma_gemm<false, true, false><<<dim3(8, 8, 1), blk, 0, stream>>>(
                QK, QK + 512, S, 512, 1024, 1024, 1024, 0L, 0L, 0L, b,
                FNUL, FNUL, scale, VNUL, 0L, nullptr);
            mfma_gemm<false, false, true><<<dim3(4, 8, 1), blk, 0, stream>>>(
                S, V, O, 1024, 1024, 1024, 512, 0L, 0L, 0L, b,
                FNUL, FNUL, 1.f, VNUL, 0L, nullptr);
            mfma_gemm<true, false, false><<<dim3(8, 4, 1), blk, 0, stream>>>(
                Wob, O, d_out, 512, 512, 512, 1024, 0L, 0L, CHW, b,
                bO, FNUL, 1.f, x, CHW, flag);
        }
    }
}

// Round 3
// 286.666 us; speedup vs baseline: 1.2625x; 1.2625x over previous
//
#include <hip/hip_runtime.h>
#include <hip/hip_bf16.h>

#define HWN    1024
#define CCH    512
#define NBATCH 16
#define NGROUP 32
#define EPSV   1e-5f

using bf16 = __hip_bfloat16;
typedef __attribute__((ext_vector_type(4))) float f32x4;
typedef __attribute__((ext_vector_type(8))) short s16x8;

// Runtime-dtyped element access: c==1 -> fp32, c==0 -> bf16 storage.
__device__ __forceinline__ float ldv(const void* p, long i, int c) {
    return c ? ((const float*)p)[i] : __bfloat162float(((const bf16*)p)[i]);
}
__device__ __forceinline__ void stv(void* p, long i, int c, float v) {
    if (c) ((float*)p)[i] = v;
    else   ((bf16*)p)[i]  = __float2bfloat16(v);
}

// async global->LDS, 16B per lane; lds dest = wave-uniform base + lane*16
__device__ __forceinline__ void glds16(const void* g, void* l) {
    __builtin_amdgcn_global_load_lds(
        (const __attribute__((address_space(1))) void*)g,
        (__attribute__((address_space(3))) void*)l, 16, 0, 0);
}

// ---------------------------------------------------------------------------
// Storage dtype detector (proven in R3). flag=1 => fp32 storage.
// ---------------------------------------------------------------------------
__global__ __launch_bounds__(256) void detect_kernel(const void* __restrict__ x,
                                                     int* __restrict__ flag)
{
    const int tid = threadIdx.x;
    const unsigned short* h = (const unsigned short*)x;
    int ok = 0;
    for (int i = tid; i < 4096; i += 256) {
        int e = (h[2 * i] >> 7) & 0xFF;
        if (e >= 100 && e <= 135) ok++;
    }
    __shared__ int red[256];
    red[tid] = ok; __syncthreads();
    for (int off = 128; off > 0; off >>= 1) {
        if (tid < off) red[tid] += red[tid + off];
        __syncthreads();
    }
    if (tid == 0) flag[0] = (red[0] < 2458) ? 1 : 0;
}

// ---------------------------------------------------------------------------
// GroupNorm stats: one block per (batch, group) -> (mean, rstd). f4-vectorized.
// ---------------------------------------------------------------------------
__global__ __launch_bounds__(256) void gn_stats_kernel(const void* __restrict__ x,
                                                       const int* __restrict__ flag,
                                                       float2* __restrict__ stats)
{
    const int f = flag[0];
    const int b = blockIdx.x >> 5, g = blockIdx.x & 31;
    const long base = ((long)b * CCH + (long)g * (CCH / NGROUP)) * HWN;
    const int tid = threadIdx.x;
    const int n = (CCH / NGROUP) * HWN;       // 16384
    float s = 0.f, ss = 0.f;
    if (f) {
        const float4* xp = (const float4*)((const float*)x + base);
        #pragma unroll
        for (int k = 0; k < 16; ++k) {
            float4 u = xp[tid + k * 256];
            s  += u.x + u.y + u.z + u.w;
            ss += u.x * u.x + u.y * u.y + u.z * u.z + u.w * u.w;
        }
    } else {
        for (int i = tid; i < n; i += 256) {
            float v = ldv(x, base + i, 0);
            s += v; ss += v * v;
        }
    }
    __shared__ float r1[256], r2[256];
    r1[tid] = s; r2[tid] = ss; __syncthreads();
    for (int off = 128; off > 0; off >>= 1) {
        if (tid < off) { r1[tid] += r1[tid + off]; r2[tid] += r2[tid + off]; }
        __syncthreads();
    }
    if (tid == 0) {
        float mean = r1[0] / n;
        float var  = r2[0] / n - mean * mean;
        stats[blockIdx.x] = make_float2(mean, rsqrtf(var + EPSV));
    }
}

// ---------------------------------------------------------------------------
// Weight/bias prep: Wqk = [Wq;Wk] bf16 [1024][512]; Wv,Wo bf16; biases f32.
// ---------------------------------------------------------------------------
__global__ __launch_bounds__(256)
void prep_kernel(const void* __restrict__ Wq, const void* __restrict__ Wk,
                 const void* __restrict__ Wv, const void* __restrict__ Wo,
                 const void* __restrict__ bq, const void* __restrict__ bk,
                 const void* __restrict__ bv, const void* __restrict__ bo,
                 const int* __restrict__ flag,
                 bf16* __restrict__ Wqk, bf16* __restrict__ Wvb, bf16* __restrict__ Wob,
                 float* __restrict__ bQK, float* __restrict__ bV, float* __restrict__ bO)
{
    const int f = flag[0];
    const int idx = blockIdx.x * 256 + threadIdx.x;
    if (idx < 524288) {
        const int r = idx >> 9, c = idx & 511;
        float v = (r < 512) ? ldv(Wq, (long)r * 512 + c, f)
                            : ldv(Wk, (long)(r - 512) * 512 + c, f);
        Wqk[idx] = __float2bfloat16(v);
    } else if (idx < 786432) {
        Wvb[idx - 524288] = __float2bfloat16(ldv(Wv, idx - 524288, f));
    } else if (idx < 1048576) {
        Wob[idx - 786432] = __float2bfloat16(ldv(Wo, idx - 786432, f));
    } else {
        const int j = idx - 1048576;
        if      (j < 512)  bQK[j]        = ldv(bq, j, f);
        else if (j < 1024) bQK[j]        = ldv(bk, j - 512, f);
        else if (j < 1536) bV[j - 1024]  = ldv(bv, j - 1024, f);
        else if (j < 2048) bO[j - 1536]  = ldv(bo, j - 1536, f);
    }
}

// ---------------------------------------------------------------------------
// GN+SiLU with transpose: x [c][i] (flag dtype) -> xn' [i][c] bf16.
// ---------------------------------------------------------------------------
__global__ __launch_bounds__(256)
void gn_apply_kernel(const void* __restrict__ x, const int* __restrict__ flag,
                     const float2* __restrict__ stats,
                     const void* __restrict__ gamma, const void* __restrict__ beta,
                     bf16* __restrict__ xn, int zb)
{
    const int f = flag[0];
    __shared__ float t[64][65];
    const int bz = blockIdx.z;
    const int bx = zb + bz;
    const int i0 = blockIdx.x * 64;
    const int c0 = blockIdx.y * 64;
    const int tid = threadIdx.x;
    const int il = tid & 63;
    const int hq = tid >> 6;              // 0..3
    #pragma unroll
    for (int r = 0; r < 16; ++r) {
        const int cl = r * 4 + hq;
        const int c = c0 + cl;
        const float2 st = stats[bx * NGROUP + (c >> 4)];
        const float ga = ldv(gamma, c, f), be = ldv(beta, c, f);
        float v = ldv(x, (long)bx * CCH * HWN + (long)c * HWN + i0 + il, f);
        v = (v - st.x) * st.y * ga + be;
        t[cl][il] = v / (1.f + __expf(-v));     // SiLU
    }
    __syncthreads();
    #pragma unroll
    for (int r = 0; r < 16; ++r) {
        const int ii = r * 4 + hq;
        xn[(long)bz * CCH * HWN + (long)(i0 + ii) * CCH + c0 + il] =
            __float2bfloat16(t[il][ii]);
    }
}

// ---------------------------------------------------------------------------
// Legacy 128x128 MFMA GEMM — kept for tier2/3 fallback paths (proven).
// ---------------------------------------------------------------------------
template<bool FINAL, bool EXPS, bool RDIV>
__global__ __launch_bounds__(256)
void mfma_gemm(const bf16* __restrict__ A, const bf16* __restrict__ B,
               void* __restrict__ C, int K,
               int lda, int ldb, int ldc,
               long sA, long sB, long sC, int z0,
               const float* __restrict__ rowBias, const float* __restrict__ colBias,
               float alpha, const void* __restrict__ resid, long sR,
               const int* __restrict__ flag)
{
    __shared__ bf16 lA[2][128 * 32];
    __shared__ bf16 lB[2][128 * 32];

    const int gx = gridDim.x, gy = gridDim.y;
    const int nwg = gx * gy * (int)gridDim.z;
    const int lin = blockIdx.x + gx * (blockIdx.y + gy * blockIdx.z);
    const int qq = nwg >> 3, rr = nwg & 7;
    const int xc = lin & 7, sq = lin >> 3;
    const int nl = (xc < rr ? xc * (qq + 1) : rr * (qq + 1) + (xc - rr) * qq) + sq;
    const int bxi = nl % gx;
    const int tt  = nl / gx;
    const int byi = tt % gy;
    const int bzi = tt / gy;

    const int tid = threadIdx.x;
    const int w   = tid >> 6;
    const int l   = tid & 63;
    const int ln  = l & 15;
    const int qd  = l >> 4;
    const int wm  = (w >> 1) * 64;
    const int wn  = (w & 1) * 64;
    const int zA  = z0 + bzi;

    const bf16* Ab = A + (long)zA * sA;
    const bf16* Bb = B + (long)zA * sB;
    const int m0 = byi * 128;
    const int n0 = bxi * 128;

    const int sr   = l >> 2;
    const int kswz = ((l & 3) ^ ((l >> 3) & 3)) * 8;
    const bf16* gA0 = Ab + (long)(m0 + w * 16 + sr) * lda + kswz;
    const bf16* gA1 = gA0 + (long)64 * lda;
    const bf16* gB0 = Bb + (long)(n0 + w * 16 + sr) * ldb + kswz;
    const bf16* gB1 = gB0 + (long)64 * ldb;

    f32x4 acc[4][4];
    #pragma unroll
    for (int i = 0; i < 4; ++i)
        #pragma unroll
        for (int j = 0; j < 4; ++j)
            acc[i][j] = (f32x4){0.f, 0.f, 0.f, 0.f};

    float rsum[4] = {0.f, 0.f, 0.f, 0.f};
    const int swA = (qd ^ ((ln >> 1) & 3)) * 8;

    glds16(gA0, &lA[0][w * 512]);
    glds16(gA1, &lA[0][2048 + w * 512]);
    glds16(gB0, &lB[0][w * 512]);
    glds16(gB1, &lB[0][2048 + w * 512]);

    const int NK = K >> 5;
    for (int t = 0; t < NK; ++t) {
        const int p = t & 1;
        __syncthreads();
        if (t + 1 < NK) {
            const int kk = (t + 1) << 5;
            glds16(gA0 + kk, &lA[p ^ 1][w * 512]);
            glds16(gA1 + kk, &lA[p ^ 1][2048 + w * 512]);
            glds16(gB0 + kk, &lB[p ^ 1][w * 512]);
            glds16(gB1 + kk, &lB[p ^ 1][2048 + w * 512]);
        }
        s16x8 af[4], bfr[4];
        #pragma unroll
        for (int i = 0; i < 4; ++i)
            af[i] = *(const s16x8*)&lA[p][(wm + i * 16 + ln) * 32 + swA];
        #pragma unroll
        for (int j = 0; j < 4; ++j)
            bfr[j] = *(const s16x8*)&lB[p][(wn + j * 16 + ln) * 32 + swA];
        if (RDIV) {
            #pragma unroll
            for (int i = 0; i < 4; ++i) {
                union { s16x8 v; unsigned u[4]; } cv; cv.v = af[i];
                #pragma unroll
                for (int wd = 0; wd < 4; ++wd) {
                    rsum[i] += __uint_as_float(cv.u[wd] << 16);
                    rsum[i] += __uint_as_float(cv.u[wd] & 0xffff0000u);
                }
            }
        }
        #pragma unroll
        for (int i = 0; i < 4; ++i)
            #pragma unroll
            for (int j = 0; j < 4; ++j)
                acc[i][j] = __builtin_amdgcn_mfma_f32_16x16x32_bf16(
                    af[i], bfr[j], acc[i][j], 0, 0, 0);
    }

    if (RDIV) {
        #pragma unroll
        for (int i = 0; i < 4; ++i) {
            rsum[i] += __shfl_xor(rsum[i], 16);
            rsum[i] += __shfl_xor(rsum[i], 32);
        }
    }

    const int f = (FINAL && flag) ? flag[0] : 0;
    #pragma unroll
    for (int i = 0; i < 4; ++i) {
        #pragma unroll
        for (int r = 0; r < 4; ++r) {
            const int m = m0 + wm + i * 16 + qd * 4 + r;
            const float rb = rowBias ? rowBias[m] : 0.f;
            const float inv = RDIV ? (1.f / __shfl(rsum[i], qd * 4 + r)) : 1.f;
            #pragma unroll
            for (int j = 0; j < 4; ++j) {
                const int n = n0 + wn + j * 16 + ln;
                float v = alpha * acc[i][j][r] + rb;
                if (colBias) v += colBias[n];
                if (EXPS) v = __expf(fminf(v, 60.f));
                if (RDIV) v *= inv;
                const long idx = (long)zA * sC + (long)m * ldc + n;
                if (FINAL) {
                    if (resid) v += ldv(resid, (long)zA * sR + (long)m * ldc + n, f);
                    stv(C, idx, f, v);
                } else {
                    ((bf16*)C)[idx] = __float2bfloat16(v);
                }
            }
        }
    }
}

// ---------------------------------------------------------------------------
// R8: 256x256(BM) x BN(=NBF*64) tile, BK=64, 8 waves (2M x 4N), 512 threads.
// Loop discipline = the PROVEN minimal 2-phase (m248 recipe, identical to the
// R1 128x128 kernel): __syncthreads() at tile top (compiler emits the
// vmcnt(0)+barrier drain there), then prefetch next tile, then ds_read+MFMA
// of current tile — prefetch overlaps MFMA, one drain point per tile.
// (R2's counted-vmcnt/raw-barrier variant serialized; reverted.)
// XOR swizzle keeps ds_read_b128 at 2-way bank aliasing; inverse swizzle is
// pre-applied to the GLOBAL source address (rule #21).
//   C[m][n] = alpha * sum_k A[m][k]*B[n][k]  (+biases/epilogues as flagged)
// EXPS: store exp(clamp(v,60)) — softmax numerator (denominator deferred).
// RDIV: divide by row-sum of A computed in-register from the A-fragments
//       (lane (ln,qd) covers chunk qd of every 32-k block; xor16+xor32).
// SPLITN: C/resid column index n maps to batch-split layout (n>>10 = batch).
// ---------------------------------------------------------------------------
template<int NBF, bool FINAL, bool EXPS, bool RDIV, bool SPLITN>
__global__ __launch_bounds__(512)
void gemm256(const bf16* __restrict__ A, const bf16* __restrict__ B,
             void* __restrict__ C, int K,
             int lda, int ldb, int ldc,
             long sA, long sB, long sC,
             const float* __restrict__ rowBias, const float* __restrict__ colBias,
             float alpha, const void* __restrict__ resid, long sR,
             const int* __restrict__ flag)
{
    constexpr int BN = NBF * 64;
    __shared__ bf16 lA[2][256 * 64];
    __shared__ bf16 lB[2][BN * 64];

    // XCD-bijective chunk swizzle (nwg=256 here: 32 contiguous tiles per XCD)
    const int gx = gridDim.x, gy = gridDim.y;
    const int nwg = gx * gy * (int)gridDim.z;
    const int lin = blockIdx.x + gx * (blockIdx.y + gy * blockIdx.z);
    const int qq = nwg >> 3, rr = nwg & 7;
    const int xc = lin & 7, sq = lin >> 3;
    const int nl = (xc < rr ? xc * (qq + 1) : rr * (qq + 1) + (xc - rr) * qq) + sq;
    const int bxi = nl % gx;
    const int tt  = nl / gx;
    const int byi = tt % gy;
    const int zA  = tt / gy;

    const int tid = threadIdx.x;
    const int w   = tid >> 6;                 // 0..7
    const int l   = tid & 63;
    const int ln  = l & 15;
    const int qd  = l >> 4;                   // 0..3
    const int wm  = (w >> 2) * 128;           // 0 / 128
    const int wn  = (w & 3) * (NBF * 16);     // 4 N-groups

    const bf16* Ab = A + (long)zA * sA;
    const bf16* Bb = B + (long)zA * sB;
    const int m0 = byi * 256;
    const int n0 = bxi * BN;

    // staging source: lane l covers row (l>>3) (+8 per wave-instr slot),
    // 16B chunk (l&7)^(l>>3) of the 64-elem row (inverse of the read swizzle)
    const int srow = l >> 3;
    const int kch  = ((l & 7) ^ srow) * 8;
    const bf16* gA = Ab + (long)(m0 + srow) * lda + kch;
    const bf16* gB = Bb + (long)(n0 + srow) * ldb + kch;

    auto stage = [&](int bb, int t) {
        const long ko = (long)t * 64;
        #pragma unroll
        for (int j = 0; j < 4; ++j)
            glds16(gA + (long)((j * 8 + w) * 8) * lda + ko,
                   &lA[bb][(j * 8 + w) * 512]);
        #pragma unroll
        for (int j = 0; j < NBF; ++j)
            glds16(gB + (long)((j * 8 + w) * 8) * ldb + ko,
                   &lB[bb][(j * 8 + w) * 512]);
    };

    f32x4 acc[8][NBF];
    #pragma unroll
    for (int i = 0; i < 8; ++i)
        #pragma unroll
        for (int j = 0; j < NBF; ++j)
            acc[i][j] = (f32x4){0.f, 0.f, 0.f, 0.f};
    float rsum[8];
    #pragma unroll
    for (int i = 0; i < 8; ++i) rsum[i] = 0.f;

    stage(0, 0);                               // prologue

    const int NT = K >> 6;
    for (int t = 0; t < NT; ++t) {
        const int cur = t & 1;
        __syncthreads();                       // tile t resident; prior reads done
        if (t + 1 < NT)
            stage(cur ^ 1, t + 1);             // prefetch overlaps MFMA below

        #pragma unroll
        for (int ks = 0; ks < 2; ++ks) {
            s16x8 af[8], bfr[NBF];
            const int swz = ((ks * 4 + qd) ^ (l & 7)) * 8;
            #pragma unroll
            for (int i = 0; i < 8; ++i)
                af[i] = *(const s16x8*)&lA[cur][(wm + i * 16 + ln) * 64 + swz];
            #pragma unroll
            for (int j = 0; j < NBF; ++j)
                bfr[j] = *(const s16x8*)&lB[cur][(wn + j * 16 + ln) * 64 + swz];
            if (RDIV) {                        // softmax denom partials (VALU)
                #pragma unroll
                for (int i = 0; i < 8; ++i) {
                    union { s16x8 v; unsigned u[4]; } cv; cv.v = af[i];
                    #pragma unroll
                    for (int wd = 0; wd < 4; ++wd) {
                        rsum[i] += __uint_as_float(cv.u[wd] << 16);
                        rsum[i] += __uint_as_float(cv.u[wd] & 0xffff0000u);
                    }
                }
            }
            #pragma unroll
            for (int i = 0; i < 8; ++i)
                #pragma unroll
                for (int j = 0; j < NBF; ++j)
                    acc[i][j] = __builtin_amdgcn_mfma_f32_16x16x32_bf16(
                        af[i], bfr[j], acc[i][j], 0, 0, 0);
        }
    }

    if (RDIV) {
        #pragma unroll
        for (int i = 0; i < 8; ++i) {
            rsum[i] += __shfl_xor(rsum[i], 16);
            rsum[i] += __shfl_xor(rsum[i], 32);
        }
    }

    // epilogue: C/D layout col = lane&15, row = qd*4 + reg  [m89]
    const int f = (FINAL && flag) ? flag[0] : 0;
    #pragma unroll
    for (int i = 0; i < 8; ++i) {
        #pragma unroll
        for (int r = 0; r < 4; ++r) {
            const int m = m0 + wm + i * 16 + qd * 4 + r;
            const float rb = rowBias ? rowBias[m] : 0.f;
            const float inv = RDIV ? (1.f / __shfl(rsum[i], qd * 4 + r)) : 1.f;
            #pragma unroll
            for (int j = 0; j < NBF; ++j) {
                const int n = n0 + wn + j * 16 + ln;
                float v = alpha * acc[i][j][r] + rb;
                if (colBias) v += colBias[n];
                if (EXPS) v = __expf(fminf(v, 60.f));
                if (RDIV) v *= inv;
                long idx, ridx;
                if (SPLITN) {
                    idx  = (long)(n >> 10) * sC + (long)m * ldc + (n & 1023);
                    ridx = (long)(n >> 10) * sR + (long)m * ldc + (n & 1023);
                } else {
                    idx  = (long)zA * sC + (long)m * ldc + n;
                    ridx = (long)zA * sR + (long)m * ldc + n;
                }
                if (FINAL) {
                    if (resid) v += ldv(resid, ridx, f);
                    stv(C, idx, f, v);
                } else {
                    ((bf16*)C)[idx] = __float2bfloat16(v);
                }
            }
        }
    }
}

// ---------------------------------------------------------------------------
extern "C" void kernel_launch(void* const* d_in, const int* in_sizes, int n_in,
                              void* d_out, int out_size, void* d_ws, size_t ws_size,
                              hipStream_t stream)
{
    const long NX = (long)NBATCH * CCH * HWN;
    int ix, iWq, ibq, iWk, ibk, iWv, ibv, iWo, ibo, iga, ibe;
    if (in_sizes[0] == NX) {
        ix = 0; iWq = 1; ibq = 2; iWk = 3; ibk = 4; iWv = 5; ibv = 6;
        iWo = 7; ibo = 8; iga = 9; ibe = 10;
    } else {
        iWk = 0; iWo = 1; iWq = 2; iWv = 3; ibe = 4; ibk = 5; ibo = 6;
        ibq = 7; ibv = 8; iga = 9; ix = 10;
    }
    const void* x     = d_in[ix];
    const void* Wq    = d_in[iWq];
    const void* bq    = d_in[ibq];
    const void* Wk    = d_in[iWk];
    const void* bk    = d_in[ibk];
    const void* Wv    = d_in[iWv];
    const void* bv    = d_in[ibv];
    const void* Wo    = d_in[iWo];
    const void* bo    = d_in[ibo];
    const void* gamma = d_in[iga];
    const void* beta  = d_in[ibe];

    const long CHW = (long)CCH * HWN;      // 524288
    const long NN  = (long)HWN * HWN;      // 1048576
    const size_t MB = 1ull << 20;
    char* ws = (char*)d_ws;

    bf16*   Wqk   = (bf16*)ws;                         // 1 MB
    bf16*   Wvb   = (bf16*)(ws + MB);                  // 0.5 MB
    bf16*   Wob   = (bf16*)(ws + MB + MB / 2);         // 0.5 MB
    float*  bQK   = (float*)(ws + 2 * MB);
    float*  bV    = (float*)(ws + 2 * MB + 4096);
    float*  bO    = (float*)(ws + 2 * MB + 6144);
    float2* stats = (float2*)(ws + 2 * MB + 8192);     // 4 KB
    int*    flag  = (int*)(ws + 2 * MB + 12288);

    dim3 blk(256);
    dim3 blk512(512);
    const float scale = 0.044194173824159216f;   // 512^-0.5
    const float* FNUL = nullptr;
    const void*  VNUL = nullptr;

    detect_kernel<<<dim3(1), blk, 0, stream>>>(x, flag);
    gn_stats_kernel<<<dim3(NBATCH * NGROUP), blk, 0, stream>>>(x, flag, stats);
    prep_kernel<<<dim3(4104), blk, 0, stream>>>(Wq, Wk, Wv, Wo, bq, bk, bv, bo,
                                                flag, Wqk, Wvb, Wob, bQK, bV, bO);

    const int tier = (ws_size >= 100 * MB) ? 1 : (ws_size >= 70 * MB) ? 2 : 3;

    if (tier == 1) {
        bf16* xn = (bf16*)(ws + 3 * MB);      // 16 MB [b*1024+i][c]
        bf16* Vt = (bf16*)(ws + 19 * MB);     // 16 MB [c][b*1024+j]
        bf16* QK = (bf16*)(ws + 35 * MB);     // 32 MB [b*1024+i][1024]
        bf16* S  = (bf16*)(ws + 67 * MB);     // 32 MB [b][i][j]
        bf16* O  = xn;                        // overlay: xn dead after V GEMM

        gn_apply_kernel<<<dim3(16, 8, NBATCH), blk, 0, stream>>>(
            x, flag, stats, gamma, beta, xn, 0);

        // QK' = xn' @ [Wq;Wk]^T + bias  (merged: M=16384, N=1024, K=512)
        gemm256<4, false, false, false, false><<<dim3(4, 64, 1), blk512, 0, stream>>>(
            xn, Wqk, QK, 512, 512, 512, 1024, 0L, 0L, 0L,
            FNUL, bQK, 1.f, VNUL, 0L, nullptr);
        // Vt[c][b*1024+j] = Wv @ gn(x)  (merged: M=512, N=16384, K=512)
        gemm256<2, false, false, false, false><<<dim3(128, 2, 1), blk512, 0, stream>>>(
            Wvb, xn, Vt, 512, 512, 512, 16384, 0L, 0L, 0L,
            bV, FNUL, 1.f, VNUL, 0L, nullptr);
        // S~ = exp(scale * Q' K'^T)  (per batch: M=N=1024, K=512)
        gemm256<4, false, true, false, false><<<dim3(4, 4, NBATCH), blk512, 0, stream>>>(
            QK, QK + 512, S, 512, 1024, 1024, 1024, NN, NN, NN,
            FNUL, FNUL, scale, VNUL, 0L, nullptr);
        // O' = (S~ @ Vt^T) / rowsum(S~)  (per batch: M=1024, N=512, K=1024)
        gemm256<2, false, false, true, false><<<dim3(4, 4, NBATCH), blk512, 0, stream>>>(
            S, Vt, O, 1024, 1024, 16384, 512, NN, 1024L, CHW,
            FNUL, FNUL, 1.f, VNUL, 0L, nullptr);
        // out = Wo @ O'^T + bo + x  (merged-N: M=512, N=16384, K=512)
        gemm256<2, true, false, false, true><<<dim3(128, 2, 1), blk512, 0, stream>>>(
            Wob, O, d_out, 512, 512, 512, 1024, 0L, 0L, CHW,
            bO, FNUL, 1.f, x, CHW, flag);
    } else if (tier == 2) {
        bf16* xn = (bf16*)(ws + 3 * MB);      // 16 MB [i][c] per batch
        bf16* V  = (bf16*)(ws + 19 * MB);     // 16 MB [c][j] per batch
        bf16* QK = (bf16*)(ws + 35 * MB);     // 32 MB [i][1024] per batch
        bf16* S  = (bf16*)(ws + 67 * MB);     // 2 MB
        bf16* O  = xn;

        gn_apply_kernel<<<dim3(16, 8, NBATCH), blk, 0, stream>>>(
            x, flag, stats, gamma, beta, xn, 0);
        mfma_gemm<false, false, false><<<dim3(8, 8, NBATCH), blk, 0, stream>>>(
            xn, Wqk, QK, 512, 512, 512, 1024, CHW, 0L, NN, 0,
            FNUL, bQK, 1.f, VNUL, 0L, nullptr);
        mfma_gemm<false, false, false><<<dim3(8, 4, NBATCH), blk, 0, stream>>>(
            Wvb, xn, V, 512, 512, 512, 1024, 0L, CHW, CHW, 0,
            bV, FNUL, 1.f, VNUL, 0L, nullptr);
        for (int b = 0; b < NBATCH; ++b) {
            mfma_gemm<false, true, false><<<dim3(8, 8, 1), blk, 0, stream>>>(
                QK, QK + 512, S, 512, 1024, 1024, 1024, NN, NN, 0L, b,
                FNUL, FNUL, scale, VNUL, 0L, nullptr);
            mfma_gemm<false, false, true><<<dim3(4, 8, 1), blk, 0, stream>>>(
                S, V, O, 1024, 1024, 1024, 512, 0L, CHW, CHW, b,
                FNUL, FNUL, 1.f, VNUL, 0L, nullptr);
        }
        mfma_gemm<true, false, false><<<dim3(8, 4, NBATCH), blk, 0, stream>>>(
            Wob, O, d_out, 512, 512, 512, 1024, 0L, CHW, CHW, 0,
            bO, FNUL, 1.f, x, CHW, flag);
    } else {
        // tier 3: fully per-batch (ws >= 9 MB)
        bf16* xn = (bf16*)(ws + 3 * MB);      // 1 MB
        bf16* V  = (bf16*)(ws + 4 * MB);      // 1 MB
        bf16* QK = (bf16*)(ws + 5 * MB);      // 2 MB
        bf16* S  = (bf16*)(ws + 7 * MB);      // 2 MB
        bf16* O  = xn;
        for (int b = 0; b < NBATCH; ++b) {
            gn_apply_kernel<<<dim3(16, 8, 1), blk, 0, stream>>>(
                x, flag, stats, gamma, beta, xn, b);
            mfma_gemm<false, false, false><<<dim3(8, 8, 1), blk, 0, stream>>>(
                xn, Wqk, QK, 512, 512, 512, 1024, 0L, 0L, 0L, 0,
                FNUL, bQK, 1.f, VNUL, 0L, nullptr);
            mfma_gemm<false, false, false><<<dim3(8, 4, 1), blk, 0, stream>>>(
                Wvb, xn, V, 512, 512, 512, 1024, 0L, 0L, 0L, 0,
                bV, FNUL, 1.f, VNUL, 0L, nullptr);
            mfma_gemm<false, true, false><<<dim3(8, 8, 1), blk, 0, stream>>>(
                QK, QK + 512, S, 512, 1024, 1024, 1024, 0L, 0L, 0L, b,
                FNUL, FNUL, scale, VNUL, 0L, nullptr);
            mfma_gemm<false, false, true><<<dim3(4, 8, 1), blk, 0, stream>>>(
                S, V, O, 1024, 1024, 1024, 512, 0L, 0L, 0L, b,
                FNUL, FNUL, 1.f, VNUL, 0L, nullptr);
            mfma_gemm<true, false, false><<<dim3(8, 4, 1), blk, 0, stream>>>(
                Wob, O, d_out, 512, 512, 512, 1024, 0L, 0L, CHW, b,
                bO, FNUL, 1.f, x, CHW, flag);
        }
    }
}

// Round 4
// 275.854 us; speedup vs baseline: 1.3120x; 1.0392x over previous
//
#include <hip/hip_runtime.h>
#include <hip/hip_bf16.h>

#define HWN    1024
#define CCH    512
#define NBATCH 16
#define NGROUP 32
#define EPSV   1e-5f

using bf16 = __hip_bfloat16;
typedef __attribute__((ext_vector_type(4))) float f32x4;
typedef __attribute__((ext_vector_type(8))) short s16x8;

// Runtime-dtyped element access: c==1 -> fp32, c==0 -> bf16 storage.
__device__ __forceinline__ float ldv(const void* p, long i, int c) {
    return c ? ((const float*)p)[i] : __bfloat162float(((const bf16*)p)[i]);
}
__device__ __forceinline__ void stv(void* p, long i, int c, float v) {
    if (c) ((float*)p)[i] = v;
    else   ((bf16*)p)[i]  = __float2bfloat16(v);
}

// async global->LDS, 16B per lane; lds dest = wave-uniform base + lane*16
__device__ __forceinline__ void glds16(const void* g, void* l) {
    __builtin_amdgcn_global_load_lds(
        (const __attribute__((address_space(1))) void*)g,
        (__attribute__((address_space(3))) void*)l, 16, 0, 0);
}

// ---------------------------------------------------------------------------
// Storage dtype detector (proven in R3). flag=1 => fp32 storage.
// ---------------------------------------------------------------------------
__global__ __launch_bounds__(256) void detect_kernel(const void* __restrict__ x,
                                                     int* __restrict__ flag)
{
    const int tid = threadIdx.x;
    const unsigned short* h = (const unsigned short*)x;
    int ok = 0;
    for (int i = tid; i < 4096; i += 256) {
        int e = (h[2 * i] >> 7) & 0xFF;
        if (e >= 100 && e <= 135) ok++;
    }
    __shared__ int red[256];
    red[tid] = ok; __syncthreads();
    for (int off = 128; off > 0; off >>= 1) {
        if (tid < off) red[tid] += red[tid + off];
        __syncthreads();
    }
    if (tid == 0) flag[0] = (red[0] < 2458) ? 1 : 0;
}

// ---------------------------------------------------------------------------
// GroupNorm stats: one block per (batch, group) -> (mean, rstd). f4-vectorized.
// ---------------------------------------------------------------------------
__global__ __launch_bounds__(256) void gn_stats_kernel(const void* __restrict__ x,
                                                       const int* __restrict__ flag,
                                                       float2* __restrict__ stats)
{
    const int f = flag[0];
    const int b = blockIdx.x >> 5, g = blockIdx.x & 31;
    const long base = ((long)b * CCH + (long)g * (CCH / NGROUP)) * HWN;
    const int tid = threadIdx.x;
    const int n = (CCH / NGROUP) * HWN;       // 16384
    float s = 0.f, ss = 0.f;
    if (f) {
        const float4* xp = (const float4*)((const float*)x + base);
        #pragma unroll
        for (int k = 0; k < 16; ++k) {
            float4 u = xp[tid + k * 256];
            s  += u.x + u.y + u.z + u.w;
            ss += u.x * u.x + u.y * u.y + u.z * u.z + u.w * u.w;
        }
    } else {
        for (int i = tid; i < n; i += 256) {
            float v = ldv(x, base + i, 0);
            s += v; ss += v * v;
        }
    }
    __shared__ float r1[256], r2[256];
    r1[tid] = s; r2[tid] = ss; __syncthreads();
    for (int off = 128; off > 0; off >>= 1) {
        if (tid < off) { r1[tid] += r1[tid + off]; r2[tid] += r2[tid + off]; }
        __syncthreads();
    }
    if (tid == 0) {
        float mean = r1[0] / n;
        float var  = r2[0] / n - mean * mean;
        stats[blockIdx.x] = make_float2(mean, rsqrtf(var + EPSV));
    }
}

// ---------------------------------------------------------------------------
// Weight/bias prep: Wqk = [Wq;Wk] bf16 [1024][512]; Wv,Wo bf16; biases f32.
// ---------------------------------------------------------------------------
__global__ __launch_bounds__(256)
void prep_kernel(const void* __restrict__ Wq, const void* __restrict__ Wk,
                 const void* __restrict__ Wv, const void* __restrict__ Wo,
                 const void* __restrict__ bq, const void* __restrict__ bk,
                 const void* __restrict__ bv, const void* __restrict__ bo,
                 const int* __restrict__ flag,
                 bf16* __restrict__ Wqk, bf16* __restrict__ Wvb, bf16* __restrict__ Wob,
                 float* __restrict__ bQK, float* __restrict__ bV, float* __restrict__ bO)
{
    const int f = flag[0];
    const int idx = blockIdx.x * 256 + threadIdx.x;
    if (idx < 524288) {
        const int r = idx >> 9, c = idx & 511;
        float v = (r < 512) ? ldv(Wq, (long)r * 512 + c, f)
                            : ldv(Wk, (long)(r - 512) * 512 + c, f);
        Wqk[idx] = __float2bfloat16(v);
    } else if (idx < 786432) {
        Wvb[idx - 524288] = __float2bfloat16(ldv(Wv, idx - 524288, f));
    } else if (idx < 1048576) {
        Wob[idx - 786432] = __float2bfloat16(ldv(Wo, idx - 786432, f));
    } else {
        const int j = idx - 1048576;
        if      (j < 512)  bQK[j]        = ldv(bq, j, f);
        else if (j < 1024) bQK[j]        = ldv(bk, j - 512, f);
        else if (j < 1536) bV[j - 1024]  = ldv(bv, j - 1024, f);
        else if (j < 2048) bO[j - 1536]  = ldv(bo, j - 1536, f);
    }
}

// ---------------------------------------------------------------------------
// GN+SiLU with transpose: x [c][i] (flag dtype) -> xn' [i][c] bf16.
// ---------------------------------------------------------------------------
__global__ __launch_bounds__(256)
void gn_apply_kernel(const void* __restrict__ x, const int* __restrict__ flag,
                     const float2* __restrict__ stats,
                     const void* __restrict__ gamma, const void* __restrict__ beta,
                     bf16* __restrict__ xn, int zb)
{
    const int f = flag[0];
    __shared__ float t[64][65];
    const int bz = blockIdx.z;
    const int bx = zb + bz;
    const int i0 = blockIdx.x * 64;
    const int c0 = blockIdx.y * 64;
    const int tid = threadIdx.x;
    const int il = tid & 63;
    const int hq = tid >> 6;              // 0..3
    #pragma unroll
    for (int r = 0; r < 16; ++r) {
        const int cl = r * 4 + hq;
        const int c = c0 + cl;
        const float2 st = stats[bx * NGROUP + (c >> 4)];
        const float ga = ldv(gamma, c, f), be = ldv(beta, c, f);
        float v = ldv(x, (long)bx * CCH * HWN + (long)c * HWN + i0 + il, f);
        v = (v - st.x) * st.y * ga + be;
        t[cl][il] = v / (1.f + __expf(-v));     // SiLU
    }
    __syncthreads();
    #pragma unroll
    for (int r = 0; r < 16; ++r) {
        const int ii = r * 4 + hq;
        xn[(long)bz * CCH * HWN + (long)(i0 + ii) * CCH + c0 + il] =
            __float2bfloat16(t[il][ii]);
    }
}

// ---------------------------------------------------------------------------
// MFMA TN GEMM (R5-proven core: glds16 double-buffer + XOR bank swizzle,
// 0 measured conflicts, VGPR ~80): C[m][n] = alpha * sum_k A[m][k] * B[n][k]
// 128x128 tile, BK=32, 4 waves, 16x16x32 bf16. XCD-bijective block swizzle.
// EXPS: epilogue stores exp(clamp(v)) — softmax numerator (no atomics).
// RDIV: softmax denominator via ONES-MFMA row-sum (R4): per k-tile,
//       racc[i] = mfma(af[i], ones, racc[i]) accumulates D[m][n]=sum_k P[m][k]
//       (identical in every column n). After the loop, racc[i][r] in EVERY
//       lane already holds the row-sum for m = wm+i*16+qd*4+r — exactly the
//       row the same lane writes in the epilogue. No unpack, no shfl, ~130
//       fewer VALU ops per k-tile for +4 MFMA on a 13%-busy pipe.
// ---------------------------------------------------------------------------
template<bool FINAL, bool EXPS, bool RDIV>
__global__ __launch_bounds__(256)
void mfma_gemm(const bf16* __restrict__ A, const bf16* __restrict__ B,
               void* __restrict__ C, int K,
               int lda, int ldb, int ldc,
               long sA, long sB, long sC, int z0,
               const float* __restrict__ rowBias, const float* __restrict__ colBias,
               float alpha, const void* __restrict__ resid, long sR,
               const int* __restrict__ flag)
{
    __shared__ bf16 lA[2][128 * 32];
    __shared__ bf16 lB[2][128 * 32];

    // XCD-bijective chunk swizzle (pure work permutation; m204 form)
    const int gx = gridDim.x, gy = gridDim.y;
    const int nwg = gx * gy * (int)gridDim.z;
    const int lin = blockIdx.x + gx * (blockIdx.y + gy * blockIdx.z);
    const int qq = nwg >> 3, rr = nwg & 7;
    const int xc = lin & 7, sq = lin >> 3;
    const int nl = (xc < rr ? xc * (qq + 1) : rr * (qq + 1) + (xc - rr) * qq) + sq;
    const int bxi = nl % gx;
    const int tt  = nl / gx;
    const int byi = tt % gy;
    const int bzi = tt / gy;

    const int tid = threadIdx.x;
    const int w   = tid >> 6;         // wave 0..3
    const int l   = tid & 63;
    const int ln  = l & 15;
    const int qd  = l >> 4;           // 0..3
    const int wm  = (w >> 1) * 64;
    const int wn  = (w & 1) * 64;
    const int zA  = z0 + bzi;

    const bf16* Ab = A + (long)zA * sA;
    const bf16* Bb = B + (long)zA * sB;
    const int m0 = byi * 128;
    const int n0 = bxi * 128;

    // staging: lane -> local row l>>2, LDS slot l&3 which holds swizzled kseg
    const int sr   = l >> 2;
    const int kswz = ((l & 3) ^ ((l >> 3) & 3)) * 8;   // global col offset
    const bf16* gA0 = Ab + (long)(m0 + w * 16 + sr) * lda + kswz;
    const bf16* gA1 = gA0 + (long)64 * lda;
    const bf16* gB0 = Bb + (long)(n0 + w * 16 + sr) * ldb + kswz;
    const bf16* gB1 = gB0 + (long)64 * ldb;

    f32x4 acc[4][4];
    #pragma unroll
    for (int i = 0; i < 4; ++i)
        #pragma unroll
        for (int j = 0; j < 4; ++j)
            acc[i][j] = (f32x4){0.f, 0.f, 0.f, 0.f};

    // RDIV: ones-MFMA row-sum accumulators
    f32x4 racc[4];
    #pragma unroll
    for (int i = 0; i < 4; ++i) racc[i] = (f32x4){0.f, 0.f, 0.f, 0.f};
    s16x8 ones;
    #pragma unroll
    for (int e = 0; e < 8; ++e) ones[e] = (short)0x3F80;   // bf16 1.0

    // swizzled fragment read offsets; 2-way bank aliasing only (free, m136)
    const int swA = (qd ^ ((ln >> 1) & 3)) * 8;

    // prologue: stage tile 0 into buffer 0
    glds16(gA0, &lA[0][w * 512]);
    glds16(gA1, &lA[0][2048 + w * 512]);
    glds16(gB0, &lB[0][w * 512]);
    glds16(gB1, &lB[0][2048 + w * 512]);

    const int NK = K >> 5;
    for (int t = 0; t < NK; ++t) {
        const int p = t & 1;
        __syncthreads();               // tile t resident; prior reads done
        if (t + 1 < NK) {              // stage tile t+1 (overlaps MFMA below)
            const int kk = (t + 1) << 5;
            glds16(gA0 + kk, &lA[p ^ 1][w * 512]);
            glds16(gA1 + kk, &lA[p ^ 1][2048 + w * 512]);
            glds16(gB0 + kk, &lB[p ^ 1][w * 512]);
            glds16(gB1 + kk, &lB[p ^ 1][2048 + w * 512]);
        }
        s16x8 af[4], bfr[4];
        #pragma unroll
        for (int i = 0; i < 4; ++i)
            af[i] = *(const s16x8*)&lA[p][(wm + i * 16 + ln) * 32 + swA];
        #pragma unroll
        for (int j = 0; j < 4; ++j)
            bfr[j] = *(const s16x8*)&lB[p][(wn + j * 16 + ln) * 32 + swA];
        if (RDIV) {                    // row-sum on the MFMA pipe
            #pragma unroll
            for (int i = 0; i < 4; ++i)
                racc[i] = __builtin_amdgcn_mfma_f32_16x16x32_bf16(
                    af[i], ones, racc[i], 0, 0, 0);
        }
        #pragma unroll
        for (int i = 0; i < 4; ++i)
            #pragma unroll
            for (int j = 0; j < 4; ++j)
                acc[i][j] = __builtin_amdgcn_mfma_f32_16x16x32_bf16(
                    af[i], bfr[j], acc[i][j], 0, 0, 0);
    }

    // epilogue: C/D layout col = lane&15, row = qd*4 + reg  [m89]
    const int f = (FINAL && flag) ? flag[0] : 0;
    #pragma unroll
    for (int i = 0; i < 4; ++i) {
        #pragma unroll
        for (int r = 0; r < 4; ++r) {
            const int m = m0 + wm + i * 16 + qd * 4 + r;
            const float rb = rowBias ? rowBias[m] : 0.f;
            // racc[i][r]: every column holds the row-sum for this exact m
            const float inv = RDIV ? (1.f / racc[i][r]) : 1.f;
            #pragma unroll
            for (int j = 0; j < 4; ++j) {
                const int n = n0 + wn + j * 16 + ln;
                float v = alpha * acc[i][j][r] + rb;
                if (colBias) v += colBias[n];
                if (EXPS) v = __expf(fminf(v, 60.f));
                if (RDIV) v *= inv;
                const long idx = (long)zA * sC + (long)m * ldc + n;
                if (FINAL) {
                    if (resid) v += ldv(resid, (long)zA * sR + (long)m * ldc + n, f);
                    stv(C, idx, f, v);
                } else {
                    ((bf16*)C)[idx] = __float2bfloat16(v);
                }
            }
        }
    }
}

// ---------------------------------------------------------------------------
extern "C" void kernel_launch(void* const* d_in, const int* in_sizes, int n_in,
                              void* d_out, int out_size, void* d_ws, size_t ws_size,
                              hipStream_t stream)
{
    const long NX = (long)NBATCH * CCH * HWN;
    int ix, iWq, ibq, iWk, ibk, iWv, ibv, iWo, ibo, iga, ibe;
    if (in_sizes[0] == NX) {
        ix = 0; iWq = 1; ibq = 2; iWk = 3; ibk = 4; iWv = 5; ibv = 6;
        iWo = 7; ibo = 8; iga = 9; ibe = 10;
    } else {
        iWk = 0; iWo = 1; iWq = 2; iWv = 3; ibe = 4; ibk = 5; ibo = 6;
        ibq = 7; ibv = 8; iga = 9; ix = 10;
    }
    const void* x     = d_in[ix];
    const void* Wq    = d_in[iWq];
    const void* bq    = d_in[ibq];
    const void* Wk    = d_in[iWk];
    const void* bk    = d_in[ibk];
    const void* Wv    = d_in[iWv];
    const void* bv    = d_in[ibv];
    const void* Wo    = d_in[iWo];
    const void* bo    = d_in[ibo];
    const void* gamma = d_in[iga];
    const void* beta  = d_in[ibe];

    const long CHW = (long)CCH * HWN;      // 524288
    const long NN  = (long)HWN * HWN;      // 1048576
    const size_t MB = 1ull << 20;
    char* ws = (char*)d_ws;

    bf16*   Wqk   = (bf16*)ws;                         // 1 MB
    bf16*   Wvb   = (bf16*)(ws + MB);                  // 0.5 MB
    bf16*   Wob   = (bf16*)(ws + MB + MB / 2);         // 0.5 MB
    float*  bQK   = (float*)(ws + 2 * MB);
    float*  bV    = (float*)(ws + 2 * MB + 4096);
    float*  bO    = (float*)(ws + 2 * MB + 6144);
    float2* stats = (float2*)(ws + 2 * MB + 8192);     // 4 KB
    int*    flag  = (int*)(ws + 2 * MB + 12288);

    dim3 blk(256);
    const float scale = 0.044194173824159216f;   // 512^-0.5
    const float* FNUL = nullptr;
    const void*  VNUL = nullptr;

    detect_kernel<<<dim3(1), blk, 0, stream>>>(x, flag);
    gn_stats_kernel<<<dim3(NBATCH * NGROUP), blk, 0, stream>>>(x, flag, stats);
    prep_kernel<<<dim3(4104), blk, 0, stream>>>(Wq, Wk, Wv, Wo, bq, bk, bv, bo,
                                                flag, Wqk, Wvb, Wob, bQK, bV, bO);

    const int tier = (ws_size >= 100 * MB) ? 1 : (ws_size >= 70 * MB) ? 2 : 3;

    if (tier <= 2) {
        bf16* xn = (bf16*)(ws + 3 * MB);      // 16 MB [i][c] per batch
        bf16* V  = (bf16*)(ws + 19 * MB);     // 16 MB [c][j] per batch
        bf16* QK = (bf16*)(ws + 35 * MB);     // 32 MB [i][1024] per batch
        bf16* S  = (bf16*)(ws + 67 * MB);     // 32 MB (tier1) / 2 MB (tier2)
        bf16* O  = xn;                        // overlay: xn dead after V GEMM

        gn_apply_kernel<<<dim3(16, 8, NBATCH), blk, 0, stream>>>(
            x, flag, stats, gamma, beta, xn, 0);

        // QK' = xn' @ [Wq;Wk]^T + bias  (M=1024,N=1024,K=512)
        mfma_gemm<false, false, false><<<dim3(8, 8, NBATCH), blk, 0, stream>>>(
            xn, Wqk, QK, 512, 512, 512, 1024, CHW, 0L, NN, 0,
            FNUL, bQK, 1.f, VNUL, 0L, nullptr);
        // V[c][j] = Wv @ gn(x): A=Wv, B=xn'  (M=512,N=1024,K=512)
        mfma_gemm<false, false, false><<<dim3(8, 4, NBATCH), blk, 0, stream>>>(
            Wvb, xn, V, 512, 512, 512, 1024, 0L, CHW, CHW, 0,
            bV, FNUL, 1.f, VNUL, 0L, nullptr);

        if (tier == 1) {
            // S~ = exp(scale * Q' K'^T)  (M=N=1024,K=512)
            mfma_gemm<false, true, false><<<dim3(8, 8, NBATCH), blk, 0, stream>>>(
                QK, QK + 512, S, 512, 1024, 1024, 1024, NN, NN, NN, 0,
                FNUL, FNUL, scale, VNUL, 0L, nullptr);
            // O' = (S~ @ V^T) / rowsum(S~)  (M=1024,N=512,K=1024)
            mfma_gemm<false, false, true><<<dim3(4, 8, NBATCH), blk, 0, stream>>>(
                S, V, O, 1024, 1024, 1024, 512, NN, CHW, CHW, 0,
                FNUL, FNUL, 1.f, VNUL, 0L, nullptr);
        } else {
            for (int b = 0; b < NBATCH; ++b) {
                mfma_gemm<false, true, false><<<dim3(8, 8, 1), blk, 0, stream>>>(
                    QK, QK + 512, S, 512, 1024, 1024, 1024, NN, NN, 0L, b,
                    FNUL, FNUL, scale, VNUL, 0L, nullptr);
                mfma_gemm<false, false, true><<<dim3(4, 8, 1), blk, 0, stream>>>(
                    S, V, O, 1024, 1024, 1024, 512, 0L, CHW, CHW, b,
                    FNUL, FNUL, 1.f, VNUL, 0L, nullptr);
            }
        }
        // out = Wo @ O'^T + bo + x  (M=512,N=1024,K=512), flag-dtype store
        mfma_gemm<true, false, false><<<dim3(8, 4, NBATCH), blk, 0, stream>>>(
            Wob, O, d_out, 512, 512, 512, 1024, 0L, CHW, CHW, 0,
            bO, FNUL, 1.f, x, CHW, flag);
    } else {
        // tier 3: fully per-batch (ws >= 9 MB)
        bf16* xn = (bf16*)(ws + 3 * MB);      // 1 MB
        bf16* V  = (bf16*)(ws + 4 * MB);      // 1 MB
        bf16* QK = (bf16*)(ws + 5 * MB);      // 2 MB
        bf16* S  = (bf16*)(ws + 7 * MB);      // 2 MB
        bf16* O  = xn;
        for (int b = 0; b < NBATCH; ++b) {
            gn_apply_kernel<<<dim3(16, 8, 1), blk, 0, stream>>>(
                x, flag, stats, gamma, beta, xn, b);
            mfma_gemm<false, false, false><<<dim3(8, 8, 1), blk, 0, stream>>>(
                xn, Wqk, QK, 512, 512, 512, 1024, 0L, 0L, 0L, 0,
                FNUL, bQK, 1.f, VNUL, 0L, nullptr);
            mfma_gemm<false, false, false><<<dim3(8, 4, 1), blk, 0, stream>>>(
                Wvb, xn, V, 512, 512, 512, 1024, 0L, 0L, 0L, 0,
                bV, FNUL, 1.f, VNUL, 0L, nullptr);
            mfma_gemm<false, true, false><<<dim3(8, 8, 1), blk, 0, stream>>>(
                QK, QK + 512, S, 512, 1024, 1024, 1024, 0L, 0L, 0L, b,
                FNUL, FNUL, scale, VNUL, 0L, nullptr);
            mfma_gemm<false, false, true><<<dim3(4, 8, 1), blk, 0, stream>>>(
                S, V, O, 1024, 1024, 1024, 512, 0L, 0L, 0L, b,
                FNUL, FNUL, 1.f, VNUL, 0L, nullptr);
            mfma_gemm<true, false, false><<<dim3(8, 4, 1), blk, 0, stream>>>(
                Wob, O, d_out, 512, 512, 512, 1024, 0L, 0L, CHW, b,
                bO, FNUL, 1.f, x, CHW, flag);
        }
    }
}